// Round 4
// baseline (32.376 us; speedup 1.0000x reference)
//
#include <hip/hip_runtime.h>

// SegmentationLoss: scalar = sum_{b,l,i} g[b,l,i] * sqrt(sum_f (p[b,l,f]-g[b,l,i])^2)
// input (8,16,256,256) f32, target (8,8,256,256) f32, out: 1 f32.
// Identity: sum_f (p_f - g)^2 = s2 - 2 g s1 + NF g^2,  s1=sum_f p_f, s2=sum_f p_f^2.
//
// Round-4 structure: SINGLE kernel.
//  - Pure per-thread body (round-1 style): each thread owns one float4 group,
//    24 independent 16B loads, no barriers in the hot path. 512 blocks x 256
//    (8 waves/CU; in-flight 192 KB/CU >> BW*latency ~11 KB -> BW-saturating).
//  - No second launch: threadfence-reduction "last block" pattern with
//    HIERARCHICAL counters (32 lines x 16 blocks, then 32-way master) so no
//    cache line takes more than ~32 same-address atomics (~1 us tail, vs the
//    ~14 us tail 512 same-line atomics cost in round 1).
//  - Cross-XCD partial visibility: agent-scope atomic store/load + threadfence
//    (per-XCD L2s are not coherent for plain accesses).
//  - Determinism: counters zeroed by a captured hipMemsetAsync every call;
//    final sum order is fixed (ascending index) regardless of winning block.

#define HW     (256 * 256)
#define NF     16
#define NI     8
#define BSZ    8
#define NBLK   512
#define NGRP   32
#define GRPSZ  (NBLK / NGRP)   // 16

// d_ws layout (bytes):
//   [0,    2048) : float partial[NBLK]
//   [4096, 8192) : unsigned gcnt[NGRP], one per 128 B line
//   [8192, 8196) : unsigned master
#define PART_OFF 0
#define GCNT_OFF 4096
#define MAST_OFF 8192

__global__ __launch_bounds__(256) void seg_loss_fused(const float* __restrict__ input,
                                                      const float* __restrict__ target,
                                                      float* __restrict__ out,
                                                      unsigned char* __restrict__ ws) {
    float*    partial = (float*)(ws + PART_OFF);
    unsigned* master  = (unsigned*)(ws + MAST_OFF);

    const int tid  = blockIdx.x * blockDim.x + threadIdx.x;   // 0 .. 131071
    const int loc0 = tid << 2;                                // 4 consecutive locations
    const int b    = loc0 >> 16;
    const int l    = loc0 & (HW - 1);

    const float4* ip = reinterpret_cast<const float4*>(input  + (size_t)b * NF * HW + l);
    const float4* tp = reinterpret_cast<const float4*>(target + (size_t)b * NI * HW + l);

    float4 s1 = make_float4(0.f, 0.f, 0.f, 0.f);
    float4 s2 = make_float4(0.f, 0.f, 0.f, 0.f);
#pragma unroll
    for (int f = 0; f < NF; ++f) {
        float4 p = ip[f * (HW / 4)];
        s1.x += p.x; s1.y += p.y; s1.z += p.z; s1.w += p.w;
        s2.x += p.x * p.x; s2.y += p.y * p.y; s2.z += p.z * p.z; s2.w += p.w * p.w;
    }

    float acc = 0.f;
#pragma unroll
    for (int i = 0; i < NI; ++i) {
        float4 g = tp[i * (HW / 4)];
        acc += g.x * sqrtf(fmaxf(s2.x - 2.f * g.x * s1.x + (float)NF * g.x * g.x, 0.f));
        acc += g.y * sqrtf(fmaxf(s2.y - 2.f * g.y * s1.y + (float)NF * g.y * g.y, 0.f));
        acc += g.z * sqrtf(fmaxf(s2.z - 2.f * g.z * s1.z + (float)NF * g.z * g.z, 0.f));
        acc += g.w * sqrtf(fmaxf(s2.w - 2.f * g.w * s1.w + (float)NF * g.w * g.w, 0.f));
    }

    // Wave (64-lane) reduction, then 4-wave LDS combine.
#pragma unroll
    for (int off = 32; off > 0; off >>= 1)
        acc += __shfl_down(acc, off, 64);

    __shared__ float wsum[4];
    __shared__ int   amLast;
    const int lane = threadIdx.x & 63;
    const int wid  = threadIdx.x >> 6;
    if (lane == 0) wsum[wid] = acc;
    __syncthreads();

    if (threadIdx.x == 0) {
        float bsum = wsum[0] + wsum[1] + wsum[2] + wsum[3];
        // Publish this block's partial (agent scope: cross-XCD coherent).
        __hip_atomic_store(&partial[blockIdx.x], bsum,
                           __ATOMIC_RELAXED, __HIP_MEMORY_SCOPE_AGENT);
        __threadfence();   // release: partial visible before counter bump
        unsigned* gc = (unsigned*)(ws + GCNT_OFF + (size_t)(blockIdx.x & (NGRP - 1)) * 128);
        int last = 0;
        if (atomicAdd(gc, 1u) == GRPSZ - 1) {      // last block of this group
            __threadfence();
            if (atomicAdd(master, 1u) == NGRP - 1) // last group overall
                last = 1;
        }
        amLast = last;
    }
    __syncthreads();

    if (amLast) {   // uniform across the block
        __threadfence();   // acquire: see all published partials
        float s = __hip_atomic_load(&partial[threadIdx.x],
                                    __ATOMIC_RELAXED, __HIP_MEMORY_SCOPE_AGENT)
                + __hip_atomic_load(&partial[threadIdx.x + 256],
                                    __ATOMIC_RELAXED, __HIP_MEMORY_SCOPE_AGENT);
#pragma unroll
        for (int off = 32; off > 0; off >>= 1)
            s += __shfl_down(s, off, 64);
        if (lane == 0) wsum[wid] = s;
        __syncthreads();
        if (threadIdx.x == 0)
            out[0] = wsum[0] + wsum[1] + wsum[2] + wsum[3];
    }
}

extern "C" void kernel_launch(void* const* d_in, const int* in_sizes, int n_in,
                              void* d_out, int out_size, void* d_ws, size_t ws_size,
                              hipStream_t stream) {
    const float* input  = (const float*)d_in[0];
    const float* target = (const float*)d_in[1];
    float* out = (float*)d_out;
    unsigned char* ws = (unsigned char*)d_ws;

    // Zero the group counters + master every call (captured into the graph,
    // so every replay re-zeroes them -> deterministic).
    hipMemsetAsync(ws + GCNT_OFF, 0, (MAST_OFF - GCNT_OFF) + 128, stream);

    seg_loss_fused<<<NBLK, 256, 0, stream>>>(input, target, out, ws);
}

// Round 5
// 16.320 us; speedup vs baseline: 1.9838x; 1.9838x over previous
//
#include <hip/hip_runtime.h>

// SegmentationLoss: scalar = sum_{b,l,i} g[b,l,i] * sqrt(sum_f (p[b,l,f]-g[b,l,i])^2)
// input (8,16,256,256) f32, target (8,8,256,256) f32, out: 1 f32.
// Identity: sum_f (p_f - g)^2 = s2 - 2 g s1 + NF g^2,  s1=sum_f p_f, s2=sum_f p_f^2.
//
// Round-5: two kernels (kernel boundary = the cheap coherence point; round 4's
// fused threadfence version cost +17 us). Stage1 is the round-1 pure per-thread
// body: each thread owns one float4 group, 24 independent 16B loads, zero
// barriers until the single block-reduce, zero atomics (partial per block).
// 512 blocks x 256. Stage2: one block sums the 512 partials.
//
// History: R1 24.4us (atomic tail ~15us) | R2 41.8 (4x atomics) | R3 15.7
// (2-kernel, barrier-heavy stage1) | R4 32.4 (fused threadfence - reverted).

#define HW   (256 * 256)
#define NF   16
#define NI   8
#define BSZ  8
#define NBLK 512

__global__ __launch_bounds__(256) void seg_loss_stage1(const float* __restrict__ input,
                                                       const float* __restrict__ target,
                                                       float* __restrict__ partial) {
    const int tid  = blockIdx.x * blockDim.x + threadIdx.x;   // 0 .. 131071
    const int loc0 = tid << 2;                                // 4 consecutive locations
    const int b    = loc0 >> 16;
    const int l    = loc0 & (HW - 1);

    const float4* ip = reinterpret_cast<const float4*>(input  + (size_t)b * NF * HW + l);
    const float4* tp = reinterpret_cast<const float4*>(target + (size_t)b * NI * HW + l);

    float4 s1 = make_float4(0.f, 0.f, 0.f, 0.f);
    float4 s2 = make_float4(0.f, 0.f, 0.f, 0.f);
#pragma unroll
    for (int f = 0; f < NF; ++f) {
        float4 p = ip[f * (HW / 4)];
        s1.x += p.x; s1.y += p.y; s1.z += p.z; s1.w += p.w;
        s2.x += p.x * p.x; s2.y += p.y * p.y; s2.z += p.z * p.z; s2.w += p.w * p.w;
    }

    float acc = 0.f;
#pragma unroll
    for (int i = 0; i < NI; ++i) {
        float4 g = tp[i * (HW / 4)];
        acc += g.x * sqrtf(fmaxf(s2.x - 2.f * g.x * s1.x + (float)NF * g.x * g.x, 0.f));
        acc += g.y * sqrtf(fmaxf(s2.y - 2.f * g.y * s1.y + (float)NF * g.y * g.y, 0.f));
        acc += g.z * sqrtf(fmaxf(s2.z - 2.f * g.z * s1.z + (float)NF * g.z * g.z, 0.f));
        acc += g.w * sqrtf(fmaxf(s2.w - 2.f * g.w * s1.w + (float)NF * g.w * g.w, 0.f));
    }

    // Wave (64-lane) reduction, then one LDS combine across the 4 waves.
#pragma unroll
    for (int off = 32; off > 0; off >>= 1)
        acc += __shfl_down(acc, off, 64);

    __shared__ float wsum[4];
    const int lane = threadIdx.x & 63;
    const int wid  = threadIdx.x >> 6;
    if (lane == 0) wsum[wid] = acc;
    __syncthreads();
    if (threadIdx.x == 0)
        partial[blockIdx.x] = wsum[0] + wsum[1] + wsum[2] + wsum[3];
}

__global__ __launch_bounds__(256) void seg_loss_stage2(const float* __restrict__ partial,
                                                       float* __restrict__ out) {
    float s = partial[threadIdx.x] + partial[threadIdx.x + 256];

#pragma unroll
    for (int off = 32; off > 0; off >>= 1)
        s += __shfl_down(s, off, 64);

    __shared__ float wsum[4];
    const int lane = threadIdx.x & 63;
    const int wid  = threadIdx.x >> 6;
    if (lane == 0) wsum[wid] = s;
    __syncthreads();
    if (threadIdx.x == 0)
        out[0] = wsum[0] + wsum[1] + wsum[2] + wsum[3];
}

extern "C" void kernel_launch(void* const* d_in, const int* in_sizes, int n_in,
                              void* d_out, int out_size, void* d_ws, size_t ws_size,
                              hipStream_t stream) {
    const float* input  = (const float*)d_in[0];
    const float* target = (const float*)d_in[1];
    float* out     = (float*)d_out;
    float* partial = (float*)d_ws;   // 512 floats = 2 KB scratch

    seg_loss_stage1<<<NBLK, 256, 0, stream>>>(input, target, partial);
    seg_loss_stage2<<<1, 256, 0, stream>>>(partial, out);
}